// Round 1
// baseline (251.678 us; speedup 1.0000x reference)
//
#include <hip/hip_runtime.h>
#include <math.h>

// Problem constants (from reference setup_inputs)
#define NA 64     // atoms per molecule
#define NE 512    // edges per molecule
#define CW 64     // T-staging chunk width (columns)
#define NCH 8     // NE / CW
#define TCS 68    // Tc LDS row stride in floats (64 + pad, keeps 16B align, 2-way banks)
#define MS 65     // 64x64 fp64 matrix LDS row stride (doubles)

// sqrt(pi), sqrt(2), pi/(2*R_CUT) with R_CUT=10
#define SQRT_PI 1.7724538509055160273
#define SQRT_2  1.4142135623730950488
#define PI_OVER_2RC 0.15707963267948966

// One block per molecule. 256 threads.
// Algorithm: Woodbury on Ap = diag(cut) + T^T A T  (A is 64x64 SPD):
//   Ap^{-1} v = w*(v - T^T s),  s = A u,  u = M^{-1} (A (T (w*v))),  M = A + A S A,
//   S = T diag(w) T^T  (64x64),  w = 1/cut.
// Bordered system: y = Ap^{-1} b, z = Ap^{-1} 1, lam = (q - 1^T y)/(1 - 1^T z),
//   out = T(y - lam z) = p1 - lam*p2.
__global__ __launch_bounds__(256)
void qeq_kernel(const float* __restrict__ pos,
                const float* __restrict__ T,
                const float* __restrict__ eneg,
                const float* __restrict__ nattr,
                const float* __restrict__ qtot,
                const float* __restrict__ hard,
                const float* __restrict__ covr,
                const int*   __restrict__ an,
                const int*   __restrict__ eidx,
                float*       __restrict__ outp,
                double*      __restrict__ ws)
{
    const int m   = blockIdx.x;
    const int tid = threadIdx.x;

    // B2 union buffer: [T-chunk float 64x68] during staging passes,
    // [A copy / M factor fp64 64x65] during the small-matrix phase.
    __shared__ double B2[NA * MS];                 // 33280 B
    float* Tc = (float*)B2;

    __shared__ double b_s[NE];                     // 4 KB  (b = -T^T eneg)
    __shared__ double w_s[NE];                     // 4 KB  (w = 1/cut)
    __shared__ double eneg_s[NA];
    __shared__ double posd[NA * 3];
    __shared__ double sig_s[NA];
    __shared__ double dg_s[NA];
    __shared__ double t0a[NA], t0b[NA];
    __shared__ double pt[8][NA];                   // partial-reduce scratch (reused twice)
    __shared__ double ga[NA], gb[NA], ua[NA], ub[NA], sa[NA], sb[NA];
    __shared__ double invd[NA];
    __shared__ double ych[CW], zch[CW];
    __shared__ double lam_s;

    double* Aw = ws + (size_t)m * 12288;           // A  [64*64] fp64 in workspace
    double* Sw = Aw + 4096;                        // S  [64*64]
    double* Cw = Aw + 8192;                        // C = S*A [64*64]

    const float* Tm = T + (size_t)m * NA * NE;

    // ---------------- Phase 0: per-atom data ----------------
    if (tid < NA) {
        const int i = tid;
        posd[3*i+0] = (double)pos[(m*NA + i)*3 + 0];
        posd[3*i+1] = (double)pos[(m*NA + i)*3 + 1];
        posd[3*i+2] = (double)pos[(m*NA + i)*3 + 2];
        eneg_s[i]   = (double)eneg[m*NA + i];
        double r = (double)covr[an[m*NA + i]];
        sig_s[i] = r * r;
        const float* np_ = nattr + (size_t)(m*NA + i) * 10;
        float best = np_[0]; int bi = 0;
        #pragma unroll
        for (int k = 1; k < 10; ++k) { float v = np_[k]; if (v > best) { best = v; bi = k; } }
        dg_s[i] = (double)hard[bi] + 1.0 / (SQRT_PI * r);
    }
    __syncthreads();

    // ---------------- edges -> w = 1/cut ----------------
    for (int e = tid; e < NE; e += 256) {
        const int a0 = eidx[(size_t)m*2*NE + e];
        const int a1 = eidx[(size_t)m*2*NE + NE + e];
        const double dx = posd[3*a0+0] - posd[3*a1+0];
        const double dy = posd[3*a0+1] - posd[3*a1+1];
        const double dz = posd[3*a0+2] - posd[3*a1+2];
        const double d  = sqrt(dx*dx + dy*dy + dz*dz);
        const double cut = 1.0 / cos(PI_OVER_2RC * d) - 1.0;
        w_s[e] = 1.0 / cut;
    }

    // Tile mapping for all 64x64 matrix work: rows I=si+16p, cols J=sj+16q
    const int si = tid & 15, sj = tid >> 4;
    const int ti = tid & 63, tp = tid >> 6;

    // ---------------- build A -> workspace (fp64) ----------------
    #pragma unroll
    for (int p = 0; p < 4; ++p) {
        const int i = si + 16*p;
        #pragma unroll
        for (int q = 0; q < 4; ++q) {
            const int j = sj + 16*q;
            double v;
            if (i == j) {
                v = dg_s[i];
            } else {
                const double dx = posd[3*i+0] - posd[3*j+0];
                const double dy = posd[3*i+1] - posd[3*j+1];
                const double dz = posd[3*i+2] - posd[3*j+2];
                const double d  = sqrt(dx*dx + dy*dy + dz*dz);
                const double g  = sqrt(sig_s[i] + sig_s[j]);
                v = erf(d / (SQRT_2 * g)) / d;
            }
            Aw[i*NA + j] = v;
        }
    }

    // ---------------- S-pass over T chunks ----------------
    // accumulates: S tiles (regs), b, t0a = T(w*b), t0b = T(w*1)
    double acc[4][4];
    #pragma unroll
    for (int p = 0; p < 4; ++p)
        #pragma unroll
        for (int q = 0; q < 4; ++q) acc[p][q] = 0.0;
    double ta_p = 0.0, tb_p = 0.0;

    for (int c = 0; c < NCH; ++c) {
        __syncthreads();   // previous chunk's Tc reads done
        #pragma unroll
        for (int k = 0; k < 4; ++k) {
            const int l   = tid + 256*k;
            const int row = l >> 4, f4 = l & 15;
            const float4 v = *(const float4*)(Tm + row*NE + c*CW + 4*f4);
            *(float4*)&Tc[row*TCS + 4*f4] = v;
        }
        __syncthreads();
        // b for this chunk's columns
        if (tid < CW) {
            double accb = 0.0;
            for (int i = 0; i < NA; ++i)
                accb += (double)Tc[i*TCS + tid] * eneg_s[i];
            b_s[c*CW + tid] = -accb;
        }
        __syncthreads();
        // t0 partials (need b of this chunk)
        #pragma unroll
        for (int k = 0; k < 16; ++k) {
            const int el = tp*16 + k;
            const double tv = (double)Tc[ti*TCS + el];
            const double we = w_s[c*CW + el];
            ta_p += tv * (we * b_s[c*CW + el]);
            tb_p += tv * we;
        }
        // S tile accumulation
        for (int e = 0; e < CW; ++e) {
            const double we = w_s[c*CW + e];
            double av[4], bv[4];
            #pragma unroll
            for (int p = 0; p < 4; ++p) av[p] = (double)Tc[(si + 16*p)*TCS + e];
            #pragma unroll
            for (int q = 0; q < 4; ++q) bv[q] = we * (double)Tc[(sj + 16*q)*TCS + e];
            #pragma unroll
            for (int p = 0; p < 4; ++p)
                #pragma unroll
                for (int q = 0; q < 4; ++q) acc[p][q] += av[p] * bv[q];
        }
    }
    __syncthreads();

    // write S to ws; reduce t0; copy A into LDS (overwrites Tc)
    #pragma unroll
    for (int p = 0; p < 4; ++p)
        #pragma unroll
        for (int q = 0; q < 4; ++q)
            Sw[(si + 16*p)*NA + (sj + 16*q)] = acc[p][q];
    pt[tp][ti]     = ta_p;
    pt[4 + tp][ti] = tb_p;
    __syncthreads();
    if (tid < NA) {
        t0a[tid] = pt[0][tid] + pt[1][tid] + pt[2][tid] + pt[3][tid];
    } else if (tid < 128) {
        const int i = tid - 64;
        t0b[i] = pt[4][i] + pt[5][i] + pt[6][i] + pt[7][i];
    }
    for (int l = tid; l < NA*NA; l += 256)
        B2[(l >> 6)*MS + (l & 63)] = Aw[l];
    __syncthreads();   // Sw visible (vmcnt drained), A in LDS, t0 ready

    // ---------------- C = S * A -> ws ----------------
    {
        double cacc[4][4];
        #pragma unroll
        for (int p = 0; p < 4; ++p)
            #pragma unroll
            for (int q = 0; q < 4; ++q) cacc[p][q] = 0.0;
        for (int k = 0; k < NA; ++k) {
            double sv[4], avv[4];
            #pragma unroll
            for (int p = 0; p < 4; ++p) sv[p]  = Sw[(si + 16*p)*NA + k];
            #pragma unroll
            for (int q = 0; q < 4; ++q) avv[q] = B2[k*MS + (sj + 16*q)];
            #pragma unroll
            for (int p = 0; p < 4; ++p)
                #pragma unroll
                for (int q = 0; q < 4; ++q) cacc[p][q] += sv[p] * avv[q];
        }
        #pragma unroll
        for (int p = 0; p < 4; ++p)
            #pragma unroll
            for (int q = 0; q < 4; ++q)
                Cw[(si + 16*p)*NA + (sj + 16*q)] = cacc[p][q];
    }
    __syncthreads();   // Cw visible

    // ---------------- M = A + A*C  (into registers, then overwrite B2) ----------------
    {
        double macc[4][4];
        #pragma unroll
        for (int p = 0; p < 4; ++p)
            #pragma unroll
            for (int q = 0; q < 4; ++q)
                macc[p][q] = B2[(si + 16*p)*MS + (sj + 16*q)];
        for (int k = 0; k < NA; ++k) {
            double avv[4], cv[4];
            #pragma unroll
            for (int p = 0; p < 4; ++p) avv[p] = B2[(si + 16*p)*MS + k];
            #pragma unroll
            for (int q = 0; q < 4; ++q) cv[q]  = Cw[k*NA + (sj + 16*q)];
            #pragma unroll
            for (int p = 0; p < 4; ++p)
                #pragma unroll
                for (int q = 0; q < 4; ++q) macc[p][q] += avv[p] * cv[q];
        }
        __syncthreads();  // all A reads from B2 complete
        #pragma unroll
        for (int p = 0; p < 4; ++p)
            #pragma unroll
            for (int q = 0; q < 4; ++q)
                B2[(si + 16*p)*MS + (sj + 16*q)] = macc[p][q];
    }
    __syncthreads();

    // ---------------- rhs: ga = A*t0a, gb = A*t0b (A from ws) ----------------
    if (tid < 128) {
        const int i = tid & 63;
        const double* t0v = (tid < 64) ? t0a : t0b;
        double a = 0.0;
        for (int k = 0; k < NA; ++k) a += Aw[i*NA + k] * t0v[k];
        if (tid < 64) ga[i] = a; else gb[i] = a;
    }
    __syncthreads();

    // ---------------- LDL^T factorization of M (in B2, lower) ----------------
    if (tid == 0) invd[0] = 1.0 / B2[0];
    __syncthreads();
    for (int k = 0; k < NA - 1; ++k) {
        const int i = tid >> 2, q = tid & 3;
        if (i > k) {
            const double t = B2[i*MS + k] * invd[k];
            for (int j = k + 1 + q; j <= i; j += 4)
                B2[i*MS + j] -= t * B2[j*MS + k];
            if (i == k + 1 && q == 0)
                invd[k+1] = 1.0 / B2[(k+1)*MS + (k+1)];
        }
        __syncthreads();
    }

    // ---------------- forward: L h = g (unit-lower, h stays in ga/gb) ----------------
    for (int j = 0; j < NA - 1; ++j) {
        const double fa = ga[j] * invd[j];
        const double fb = gb[j] * invd[j];
        if (tid < NA) {
            if (tid > j) ga[tid] -= B2[tid*MS + j] * fa;
        } else if (tid < 128) {
            const int i = tid - 64;
            if (i > j) gb[i] -= B2[i*MS + j] * fb;
        }
        __syncthreads();
    }
    // ---------------- backward: L^T u = D^{-1} h ----------------
    for (int j = NA - 1; j >= 0; --j) {
        const double xa = ga[j] * invd[j];
        const double xb = gb[j] * invd[j];
        if (tid == 0) ua[j] = xa;
        if (tid == 1) ub[j] = xb;
        if (tid < NA) {
            if (tid < j) ga[tid] -= B2[j*MS + tid] * xa;
        } else if (tid < 128) {
            const int i = tid - 64;
            if (i < j) gb[i] -= B2[j*MS + i] * xb;
        }
        __syncthreads();
    }

    // ---------------- s = A * u ----------------
    if (tid < 128) {
        const int i = tid & 63;
        const double* uv = (tid < 64) ? ua : ub;
        double a = 0.0;
        for (int k = 0; k < NA; ++k) a += Aw[i*NA + k] * uv[k];
        if (tid < 64) sa[i] = a; else sb[i] = a;
    }
    __syncthreads();

    // ---------------- yz-pass over T chunks ----------------
    // y = w*(b - T^T sa), z = w*(1 - T^T sb); accumulate sums and p1 = T y, p2 = T z
    double sYp = 0.0, sZp = 0.0, p1p = 0.0, p2p = 0.0;
    for (int c = 0; c < NCH; ++c) {
        __syncthreads();   // M factor / previous chunk dead
        #pragma unroll
        for (int k = 0; k < 4; ++k) {
            const int l   = tid + 256*k;
            const int row = l >> 4, f4 = l & 15;
            const float4 v = *(const float4*)(Tm + row*NE + c*CW + 4*f4);
            *(float4*)&Tc[row*TCS + 4*f4] = v;
        }
        __syncthreads();
        if (tid < CW) {
            const int e = c*CW + tid;
            double da = 0.0, db = 0.0;
            for (int i = 0; i < NA; ++i) {
                const double tv = (double)Tc[i*TCS + tid];
                da += tv * sa[i];
                db += tv * sb[i];
            }
            const double yv = w_s[e] * (b_s[e] - da);
            const double zv = w_s[e] * (1.0 - db);
            ych[tid] = yv; zch[tid] = zv;
            sYp += yv; sZp += zv;
        }
        __syncthreads();
        #pragma unroll
        for (int k = 0; k < 16; ++k) {
            const int el = tp*16 + k;
            const double tv = (double)Tc[ti*TCS + el];
            p1p += tv * ych[el];
            p2p += tv * zch[el];
        }
    }
    __syncthreads();

    // ---------------- lambda and output ----------------
    if (tid < 64) {
        double vy = sYp, vz = sZp;
        #pragma unroll
        for (int off = 32; off > 0; off >>= 1) {
            vy += __shfl_down(vy, off, 64);
            vz += __shfl_down(vz, off, 64);
        }
        if (tid == 0) {
            const double q = (double)qtot[m];
            lam_s = (q - vy) / (1.0 - vz);
        }
    }
    pt[tp][ti]     = p1p;
    pt[4 + tp][ti] = p2p;
    __syncthreads();
    if (tid < NA) {
        const double p1 = pt[0][tid] + pt[1][tid] + pt[2][tid] + pt[3][tid];
        const double p2 = pt[4][tid] + pt[5][tid] + pt[6][tid] + pt[7][tid];
        outp[m*NA + tid] = (float)(p1 - lam_s * p2);
    }
}

extern "C" void kernel_launch(void* const* d_in, const int* in_sizes, int n_in,
                              void* d_out, int out_size, void* d_ws, size_t ws_size,
                              hipStream_t stream) {
    const float* pos  = (const float*)d_in[0];
    const float* T    = (const float*)d_in[1];
    const float* eneg = (const float*)d_in[2];
    const float* nat  = (const float*)d_in[3];
    const float* qt   = (const float*)d_in[4];
    // d_in[5] is 'p' (unused)
    const float* hard = (const float*)d_in[6];
    const float* covr = (const float*)d_in[7];
    const int*   an   = (const int*)d_in[8];
    const int*   eidx = (const int*)d_in[9];
    float* outp = (float*)d_out;
    (void)n_in; (void)out_size; (void)ws_size;

    const int B = in_sizes[4];   // total_charge has one element per molecule
    // ws usage: B * 3 * 64*64 doubles = 25.2 MB for B=256 (A, S, C per molecule)
    qeq_kernel<<<dim3(B), dim3(256), 0, stream>>>(pos, T, eneg, nat, qt, hard,
                                                  covr, an, eidx, outp,
                                                  (double*)d_ws);
}

// Round 3
// 202.951 us; speedup vs baseline: 1.2401x; 1.2401x over previous
//
#include <hip/hip_runtime.h>
#include <math.h>

// Problem constants: B molecules, N=64 atoms, E=512 edges, R_CUT=10
#define SQRT_PI 1.7724538509055160273
#define SQRT_2  1.4142135623730950488
#define PI_OVER_2RC 0.15707963267948966

// ws layout (doubles), B = #molecules:
//   Spart : [2][B][4096]   per-slice Gram partials
//   t0p   : [2][B][128]    per-slice T(w*b) | T(w*1) partials
//   w     : [B][512]
//   b     : [B][512]
//   sa/sb : [B][128]
// total = B * 9600 doubles = 19.66 MB @ B=256

__device__ __forceinline__ double bcast64(double v, int lane) {
    union { double d; unsigned int u[2]; } a, r;
    a.d = v;
    r.u[0] = __builtin_amdgcn_readlane(a.u[0], lane);
    r.u[1] = __builtin_amdgcn_readlane(a.u[1], lane);
    return r.d;
}

__device__ __forceinline__ double a_entry(int i, int j, const double* posd,
                                          const double* sig, const double* dg) {
    if (i == j) return dg[i];
    double dx = posd[3*i+0]-posd[3*j+0];
    double dy = posd[3*i+1]-posd[3*j+1];
    double dz = posd[3*i+2]-posd[3*j+2];
    double d  = sqrt(dx*dx+dy*dy+dz*dz);
    double g  = sqrt(sig[i]+sig[j]);
    return erf(d/(SQRT_2*g))/d;
}

// ---------------- K1: per-(mol, slice) f64 Gram + w,b,t0 ----------------
// grid = 2B blocks of 256; slice = 256 edges. Full f64 products (T exact f32
// converted, w applied in f64); symmetric 10-tile accumulation + mirror write.
__global__ __launch_bounds__(256, 2)
void k1_gram(const float* __restrict__ pos, const float* __restrict__ T,
             const float* __restrict__ eneg, const int* __restrict__ eidx,
             double* __restrict__ ws)
{
    const int bx = blockIdx.x;
    const int m = bx >> 1, s = bx & 1;
    const int Bm = gridDim.x >> 1;
    const int tid = threadIdx.x;

    __shared__ float  Tch[64*68];      // raw T chunk (exact f32)
    __shared__ double posd[192];
    __shared__ double eneg_s[64];
    __shared__ double w_sl[256];       // w for slice edges (f64)
    __shared__ double wb[64];          // w*b for current chunk
    __shared__ double ptr_[2][4][64];  // t0 reduction scratch

    const float* Tm = T + (size_t)m*64*512;
    double* wv = ws + (size_t)2*Bm*4096 + (size_t)2*Bm*128 + (size_t)m*512;
    double* bv = wv + (size_t)Bm*512;

    if (tid < 64) {
        posd[3*tid+0] = (double)pos[(m*64+tid)*3+0];
        posd[3*tid+1] = (double)pos[(m*64+tid)*3+1];
        posd[3*tid+2] = (double)pos[(m*64+tid)*3+2];
        eneg_s[tid]   = (double)eneg[m*64+tid];
    }
    __syncthreads();

    // per-edge w = 1/cut for this slice (1 edge/thread), all f64
    {
        const int e = s*256 + tid;
        const int a0 = eidx[(size_t)m*1024 + e];
        const int a1 = eidx[(size_t)m*1024 + 512 + e];
        double dx = posd[3*a0+0]-posd[3*a1+0];
        double dy = posd[3*a0+1]-posd[3*a1+1];
        double dz = posd[3*a0+2]-posd[3*a1+2];
        double d  = sqrt(dx*dx+dy*dy+dz*dz);
        double w  = 1.0 / (1.0/cos(PI_OVER_2RC*d) - 1.0);
        wv[e] = w;
        w_sl[tid] = w;
    }

    const int si = tid & 15, sj = tid >> 4;
    const int ti = tid & 63, tg = tid >> 6;

    // symmetric tile list (p<=q): 10 of 16 tiles
    const int PP_[10] = {0,0,0,0,1,1,1,2,2,3};
    const int QQ_[10] = {0,1,2,3,1,2,3,2,3,3};
    double acc[10];
    #pragma unroll
    for (int k = 0; k < 10; ++k) acc[k] = 0.0;
    double t0a_p = 0.0, t0b_p = 0.0;

    for (int cc = 0; cc < 4; ++cc) {
        const int gch = s*4 + cc;
        __syncthreads();    // Tch/wb free (also orders w_sl writes on cc=0)
        #pragma unroll
        for (int k = 0; k < 4; ++k) {
            int l = tid + 256*k, row = l >> 4, c4 = (l & 15)*4;
            float4 v = *(const float4*)&Tm[row*512 + gch*64 + c4];
            *(float4*)&Tch[row*68 + c4] = v;
        }
        __syncthreads();
        // b dots (raw T, f64): 4 threads per edge
        {
            int ed = tid >> 2, part = tid & 3;
            double a = 0.0;
            #pragma unroll
            for (int ii = 0; ii < 16; ++ii) {
                int i = part*16 + ii;
                a += (double)Tch[i*68 + ed] * eneg_s[i];
            }
            a += __shfl_down(a, 2);
            a += __shfl_down(a, 1);
            if (part == 0) {
                double b = -a;
                bv[s*256 + cc*64 + ed] = b;
                wb[ed] = w_sl[cc*64 + ed] * b;
            }
        }
        __syncthreads();
        // Gram: full f64, 10 symmetric tiles
        for (int e4 = 0; e4 < 16; ++e4) {
            float4 av4[4], bv4[4];
            #pragma unroll
            for (int p = 0; p < 4; ++p) av4[p] = *(float4*)&Tch[(si+16*p)*68 + e4*4];
            #pragma unroll
            for (int q = 0; q < 4; ++q) bv4[q] = *(float4*)&Tch[(sj+16*q)*68 + e4*4];
            #pragma unroll
            for (int t = 0; t < 4; ++t) {
                const double we = w_sl[cc*64 + e4*4 + t];
                double ad[4], bd[4];
                #pragma unroll
                for (int p = 0; p < 4; ++p) ad[p] = (double)((const float*)&av4[p])[t];
                #pragma unroll
                for (int q = 0; q < 4; ++q) bd[q] = we * (double)((const float*)&bv4[q])[t];
                #pragma unroll
                for (int k = 0; k < 10; ++k) acc[k] += ad[PP_[k]] * bd[QQ_[k]];
            }
        }
        // t0 partials (raw T, f64): t0a = sum T*(w*b), t0b = sum T*w
        #pragma unroll
        for (int k = 0; k < 16; ++k) {
            int e = tg*16 + k;
            double tv = (double)Tch[ti*68 + e];
            t0a_p += tv * wb[e];
            t0b_p += tv * w_sl[cc*64 + e];
        }
    }
    __syncthreads();

    double* Sp = ws + ((size_t)(s*Bm + m))*4096;
    #pragma unroll
    for (int k = 0; k < 10; ++k) {
        int i = si + 16*PP_[k], j = sj + 16*QQ_[k];
        Sp[i*64 + j] = acc[k];
        if (PP_[k] != QQ_[k]) Sp[j*64 + i] = acc[k];   // mirror (S symmetric)
    }

    ptr_[0][tg][ti] = t0a_p;
    ptr_[1][tg][ti] = t0b_p;
    __syncthreads();
    double* t0p = ws + (size_t)2*Bm*4096 + ((size_t)(s*Bm + m))*128;
    if (tid < 64) {
        t0p[tid] = ptr_[0][0][tid]+ptr_[0][1][tid]+ptr_[0][2][tid]+ptr_[0][3][tid];
    } else if (tid < 128) {
        int i = tid - 64;
        t0p[64+i] = ptr_[1][0][i]+ptr_[1][1][i]+ptr_[1][2][i]+ptr_[1][3][i];
    }
}

// ---------------- K2: assemble M, blocked LDL^T, solve, s = A*u ----------------
__global__ __launch_bounds__(256, 1)
void k2_solve(const float* __restrict__ pos, const float* __restrict__ nattr,
              const float* __restrict__ hard, const float* __restrict__ covr,
              const int* __restrict__ an, double* __restrict__ ws)
{
    const int m = blockIdx.x, tid = threadIdx.x;
    const int Bm = gridDim.x;

    __shared__ double AB[64*65];     // A, later M/L
    __shared__ double SP[16*65];     // S panel
    __shared__ double PP[64*17];     // P = A*S panel
    __shared__ double t0a_s[64], t0b_s[64], ga_s[64], gb_s[64], ua_s[64], ub_s[64];
    __shared__ double dinv_s[64], dvec_s[64];
    __shared__ double posd[192], sig_s[64], dg_s[64];
    __shared__ double pt[2][4][64];

    if (tid < 64) {
        posd[3*tid+0] = (double)pos[(m*64+tid)*3+0];
        posd[3*tid+1] = (double)pos[(m*64+tid)*3+1];
        posd[3*tid+2] = (double)pos[(m*64+tid)*3+2];
        double r = (double)covr[an[m*64+tid]];
        sig_s[tid] = r*r;
        const float* np_ = nattr + (size_t)(m*64+tid)*10;
        float best = np_[0]; int bi = 0;
        #pragma unroll
        for (int k = 1; k < 10; ++k) { float v = np_[k]; if (v > best) { best = v; bi = k; } }
        dg_s[tid] = (double)hard[bi] + 1.0/(SQRT_PI*r);
    }
    __syncthreads();

    const int si = tid & 15, sj = tid >> 4;
    // build A
    #pragma unroll
    for (int p = 0; p < 4; ++p) {
        int i = si + 16*p;
        #pragma unroll
        for (int q = 0; q < 4; ++q) {
            int j = sj + 16*q;
            AB[i*65+j] = a_entry(i, j, posd, sig_s, dg_s);
        }
    }
    // t0 = sum of slice partials
    const double* t0p0 = ws + (size_t)2*Bm*4096 + (size_t)m*128;
    const double* t0p1 = ws + (size_t)2*Bm*4096 + (size_t)(Bm + m)*128;
    if (tid < 128) {
        double v = t0p0[tid] + t0p1[tid];
        if (tid < 64) t0a_s[tid] = v; else t0b_s[tid-64] = v;
    }
    __syncthreads();
    // g = A*t0 (while A live)
    if (tid < 128) {
        int i = tid & 63;
        const double* t0 = (tid < 64) ? t0a_s : t0b_s;
        double a = 0.0;
        for (int k = 0; k < 64; ++k) a += AB[i*65+k]*t0[k];
        if (tid < 64) ga_s[i] = a; else gb_s[i] = a;
    }
    // M accumulator init = A tile
    double macc[4][4];
    #pragma unroll
    for (int p = 0; p < 4; ++p)
        #pragma unroll
        for (int q = 0; q < 4; ++q) macc[p][q] = AB[(si+16*p)*65 + (sj+16*q)];
    __syncthreads();

    // M = A + A*S*A via 16-wide panels
    const double* Sp0 = ws + (size_t)m*4096;
    const double* Sp1 = ws + (size_t)(Bm + m)*4096;
    for (int kp = 0; kp < 4; ++kp) {
        for (int l = tid; l < 1024; l += 256) {
            int c = l >> 6, k = l & 63;
            SP[c*65 + k] = Sp0[(kp*16+c)*64 + k] + Sp1[(kp*16+c)*64 + k];
        }
        __syncthreads();
        {   // PP[i][c] = sum_k A[i][k]*S[k][kp*16+c]  (S symmetric: SP[c][k])
            int c = tid & 15, ig = tid >> 4;
            double pv[4] = {0.0, 0.0, 0.0, 0.0};
            for (int k = 0; k < 64; ++k) {
                double sv = SP[c*65 + k];
                #pragma unroll
                for (int r = 0; r < 4; ++r) pv[r] += AB[(ig*4+r)*65 + k] * sv;
            }
            #pragma unroll
            for (int r = 0; r < 4; ++r) PP[(ig*4+r)*17 + c] = pv[r];
        }
        __syncthreads();
        for (int c = 0; c < 16; ++c) {
            double la[4], lb[4];
            #pragma unroll
            for (int p = 0; p < 4; ++p) la[p] = PP[(si+16*p)*17 + c];
            #pragma unroll
            for (int q = 0; q < 4; ++q) lb[q] = AB[(kp*16+c)*65 + (sj+16*q)];
            #pragma unroll
            for (int p = 0; p < 4; ++p)
                #pragma unroll
                for (int q = 0; q < 4; ++q) macc[p][q] += la[p]*lb[q];
        }
        __syncthreads();
    }
    // overwrite A with M
    #pragma unroll
    for (int p = 0; p < 4; ++p)
        #pragma unroll
        for (int q = 0; q < 4; ++q)
            AB[(si+16*p)*65 + (sj+16*q)] = macc[p][q];
    __syncthreads();

    // blocked LDL^T: 16-col panels factored in wave0 (readlane bcast), trailing by all
    for (int pb = 0; pb < 4; ++pb) {
        const int kb = pb*16;
        if (tid < 64) {
            const int i = tid;
            double pr[16];
            #pragma unroll
            for (int c = 0; c < 16; ++c) pr[c] = AB[i*65 + kb + c];
            #pragma unroll
            for (int c = 0; c < 16; ++c) {
                const int k = kb + c;
                const double Dk = bcast64(pr[c], k);
                const double di = 1.0 / Dk;
                if (i == k) { dinv_s[k] = di; dvec_s[k] = Dk; }
                const double lik = pr[c] * di;
                #pragma unroll
                for (int j = c+1; j < 16; ++j) {
                    const double mkj = bcast64(pr[j], k);
                    if (i > k) pr[j] -= lik * mkj;
                }
                if (i > k) pr[c] = lik;
            }
            #pragma unroll
            for (int c = 0; c < 16; ++c) AB[i*65 + kb + c] = pr[c];
        }
        __syncthreads();
        const int lim = kb + 16;
        if (lim < 64) {
            double tacc[4][4];
            #pragma unroll
            for (int p = 0; p < 4; ++p)
                #pragma unroll
                for (int q = 0; q < 4; ++q) tacc[p][q] = 0.0;
            for (int c = 0; c < 16; ++c) {
                const double dv = dvec_s[kb + c];
                double la[4], lb[4];
                #pragma unroll
                for (int p = 0; p < 4; ++p) la[p] = AB[(si+16*p)*65 + kb + c];
                #pragma unroll
                for (int q = 0; q < 4; ++q) lb[q] = AB[(sj+16*q)*65 + kb + c] * dv;
                #pragma unroll
                for (int p = 0; p < 4; ++p)
                    #pragma unroll
                    for (int q = 0; q < 4; ++q) tacc[p][q] += la[p]*lb[q];
            }
            #pragma unroll
            for (int p = 0; p < 4; ++p) {
                int i = si + 16*p;
                if (i >= lim) {
                    #pragma unroll
                    for (int q = 0; q < 4; ++q) {
                        int j = sj + 16*q;
                        if (j >= lim) AB[i*65+j] -= tacc[p][q];
                    }
                }
            }
        }
        __syncthreads();
    }

    // solves in wave0: L z = g ; u' = D^-1 z ; L^T u = u'
    if (tid < 64) {
        const int i = tid;
        double ha = ga_s[i], hb = gb_s[i];
        #pragma unroll
        for (int j = 0; j < 63; ++j) {
            double xa = bcast64(ha, j), xb = bcast64(hb, j);
            double lij = (i > j) ? AB[i*65+j] : 0.0;
            ha -= lij*xa; hb -= lij*xb;
        }
        double di = dinv_s[i];
        ha *= di; hb *= di;
        #pragma unroll
        for (int j = 63; j > 0; --j) {
            double xa = bcast64(ha, j), xb = bcast64(hb, j);
            double lji = (i < j) ? AB[j*65+i] : 0.0;
            ha -= lji*xa; hb -= lji*xb;
        }
        ua_s[i] = ha; ub_s[i] = hb;
    }
    __syncthreads();

    // s = A*u with recomputed A entries (A was overwritten)
    {
        int i = tid & 63, jg = tid >> 6;
        double s1 = 0.0, s2 = 0.0;
        for (int jj = 0; jj < 16; ++jj) {
            int j = jg*16 + jj;
            double a = a_entry(i, j, posd, sig_s, dg_s);
            s1 += a * ua_s[j];
            s2 += a * ub_s[j];
        }
        pt[0][jg][i] = s1;
        pt[1][jg][i] = s2;
    }
    __syncthreads();
    double* sav = ws + (size_t)2*Bm*4096 + (size_t)2*Bm*128 + (size_t)2*Bm*512 + (size_t)m*128;
    if (tid < 64) {
        sav[tid] = pt[0][0][tid]+pt[0][1][tid]+pt[0][2][tid]+pt[0][3][tid];
    } else if (tid < 128) {
        int i = tid - 64;
        sav[64+i] = pt[1][0][i]+pt[1][1][i]+pt[1][2][i]+pt[1][3][i];
    }
}

// ---------------- K3: y/z pass, lambda, output ----------------
__global__ __launch_bounds__(512, 2)
void k3_out(const float* __restrict__ T, const float* __restrict__ qtot,
            const double* __restrict__ ws, float* __restrict__ outp)
{
    const int m = blockIdx.x, tid = threadIdx.x;
    const int Bm = gridDim.x;

    __shared__ float  Tch[64*68];
    __shared__ double w_s[512], b_s[512];
    __shared__ double sa_s[64], sb_s[64];
    __shared__ double ych[64], zch[64];
    __shared__ double syp[64], szp[64];
    __shared__ double pt[2][8][64];
    __shared__ double lam_s;

    const float* Tm = T + (size_t)m*64*512;
    const double* wv  = ws + (size_t)2*Bm*4096 + (size_t)2*Bm*128 + (size_t)m*512;
    const double* bvv = wv + (size_t)Bm*512;
    const double* sav = ws + (size_t)2*Bm*4096 + (size_t)2*Bm*128 + (size_t)2*Bm*512 + (size_t)m*128;

    w_s[tid] = wv[tid];
    b_s[tid] = bvv[tid];
    if (tid < 128) {
        if (tid < 64) sa_s[tid] = sav[tid];
        else          sb_s[tid-64] = sav[tid];
    }

    const int ed = tid >> 3, part = tid & 7;
    const int ti = tid & 63, tg = tid >> 6;
    double sY = 0.0, sZ = 0.0, p1p = 0.0, p2p = 0.0;

    for (int ch = 0; ch < 8; ++ch) {
        __syncthreads();
        #pragma unroll
        for (int k = 0; k < 2; ++k) {
            int l = tid + 512*k, row = l >> 4, c4 = (l & 15)*4;
            float4 v = *(const float4*)&Tm[row*512 + ch*64 + c4];
            *(float4*)&Tch[row*68 + c4] = v;
        }
        __syncthreads();
        {
            double da = 0.0, db = 0.0;
            #pragma unroll
            for (int ii = 0; ii < 8; ++ii) {
                int i = part*8 + ii;
                double tv = (double)Tch[i*68 + ed];
                da += tv * sa_s[i];
                db += tv * sb_s[i];
            }
            da += __shfl_down(da, 4); da += __shfl_down(da, 2); da += __shfl_down(da, 1);
            db += __shfl_down(db, 4); db += __shfl_down(db, 2); db += __shfl_down(db, 1);
            if (part == 0) {
                int e = ch*64 + ed;
                double yv = w_s[e]*(b_s[e] - da);
                double zv = w_s[e]*(1.0 - db);
                ych[ed] = yv; zch[ed] = zv;
                sY += yv; sZ += zv;
            }
        }
        __syncthreads();
        #pragma unroll
        for (int k = 0; k < 8; ++k) {
            int e = tg*8 + k;
            double tv = (double)Tch[ti*68 + e];
            p1p += tv * ych[e];
            p2p += tv * zch[e];
        }
    }
    if (part == 0) { syp[ed] = sY; szp[ed] = sZ; }
    pt[0][tg][ti] = p1p;
    pt[1][tg][ti] = p2p;
    __syncthreads();
    if (tid < 64) {
        double vy = syp[tid], vz = szp[tid];
        #pragma unroll
        for (int off = 32; off > 0; off >>= 1) {
            vy += __shfl_down(vy, off);
            vz += __shfl_down(vz, off);
        }
        if (tid == 0) lam_s = ((double)qtot[m] - vy) / (1.0 - vz);
    }
    __syncthreads();
    if (tid < 64) {
        double p1 = 0.0, p2 = 0.0;
        #pragma unroll
        for (int g = 0; g < 8; ++g) { p1 += pt[0][g][tid]; p2 += pt[1][g][tid]; }
        outp[m*64 + tid] = (float)(p1 - lam_s*p2);
    }
}

extern "C" void kernel_launch(void* const* d_in, const int* in_sizes, int n_in,
                              void* d_out, int out_size, void* d_ws, size_t ws_size,
                              hipStream_t stream) {
    const float* pos  = (const float*)d_in[0];
    const float* T    = (const float*)d_in[1];
    const float* eneg = (const float*)d_in[2];
    const float* nat  = (const float*)d_in[3];
    const float* qt   = (const float*)d_in[4];
    // d_in[5] 'p' unused
    const float* hard = (const float*)d_in[6];
    const float* covr = (const float*)d_in[7];
    const int*   an   = (const int*)d_in[8];
    const int*   eidx = (const int*)d_in[9];
    float* outp = (float*)d_out;
    (void)n_in; (void)out_size; (void)ws_size;

    const int B = in_sizes[4];
    double* ws = (double*)d_ws;   // needs B*9600*8 bytes = 19.7 MB @ B=256

    k1_gram<<<dim3(2*B), dim3(256), 0, stream>>>(pos, T, eneg, eidx, ws);
    k2_solve<<<dim3(B), dim3(256), 0, stream>>>(pos, nat, hard, covr, an, ws);
    k3_out<<<dim3(B), dim3(512), 0, stream>>>(T, qt, ws, outp);
}